// Round 5
// baseline (1941.604 us; speedup 1.0000x reference)
//
#include <hip/hip_runtime.h>
#include <hip/hip_bf16.h>

#define B_SZ 512
#define T_SZ 512
#define D_SZ 256
#define H_SZ 200
#define G4   800   // 4*H
#define NSUB 50    // gate subtiles of 16
#define GST8 808   // gates stride (floats) per batch
#define HTS  232   // hT row stride (shorts)
#define BS   8     // steps per LDS staging block

typedef __attribute__((ext_vector_type(8))) short short8;
typedef __attribute__((ext_vector_type(4))) short short4v;
typedef __attribute__((ext_vector_type(4))) float f32x4;

__device__ __forceinline__ unsigned short f2bf(float x) {
    unsigned u = __builtin_bit_cast(unsigned, x);
    unsigned r = (u + 0x7FFFu + ((u >> 16) & 1u)) >> 16;
    return (unsigned short)r;
}
__device__ __forceinline__ float bf2f(unsigned short s) {
    return __builtin_bit_cast(float, (unsigned)s << 16);
}
__device__ __forceinline__ float sigm(float v) { return 1.f / (1.f + __expf(-v)); }

__device__ __forceinline__ void gl_lds16(const void* g, void* l) {
    __builtin_amdgcn_global_load_lds(
        (const __attribute__((address_space(1))) unsigned int*)g,
        (__attribute__((address_space(3))) unsigned int*)l, 16, 0, 0);
}

// ---------------------------------------------------------------------------
// Kernel 0: fp32 -> bf16 conversion
// ---------------------------------------------------------------------------
__global__ __launch_bounds__(256)
void cvt_bf16(const float* __restrict__ src, unsigned short* __restrict__ dst, int n4)
{
    int i = blockIdx.x * 256 + threadIdx.x;
    const int stride = gridDim.x * 256;
    for (; i < n4; i += stride) {
        float4 v = ((const float4*)src)[i];
        unsigned a = (unsigned)f2bf(v.x) | ((unsigned)f2bf(v.y) << 16);
        unsigned b = (unsigned)f2bf(v.z) | ((unsigned)f2bf(v.w) << 16);
        ((uint2*)dst)[i] = make_uint2(a, b);
    }
}

// ---------------------------------------------------------------------------
// Kernel 1: pre = x@W_ih^T + b_ih + b_hh, bf16 MFMA
// output layout pre[tt][S(50)][q(4)][b(512)][i(4)] bf16  (g = S*16 + q*4 + i)
// ---------------------------------------------------------------------------
__global__ __launch_bounds__(256)
void pre_gemm(const unsigned short* __restrict__ xbf,
              const unsigned short* __restrict__ wbf,
              const float* __restrict__ bih, const float* __restrict__ bhh,
              unsigned short* __restrict__ pre, int t0)
{
    const int tt = blockIdx.x;
    const int t  = t0 + tt;
    const int b0 = blockIdx.y * 64;
    const int g0 = blockIdx.z * 256;

    __shared__ unsigned short Al[256 * 32];
    __shared__ unsigned short Bl[64 * 32];

    const int tid  = threadIdx.x;
    const int w    = tid >> 6;
    const int lane = tid & 63;
    const int col  = lane & 15, q = lane >> 4;

    f32x4 acc[4][4];
    #pragma unroll
    for (int i = 0; i < 4; ++i)
        #pragma unroll
        for (int j = 0; j < 4; ++j) acc[i][j] = (f32x4)0.f;

    const int arow = w * 64 + (lane >> 2);
    const int akoff = (lane & 3) * 8;
    const int brow = b0 + w * 16 + (lane >> 2);

    for (int kc = 0; kc < 8; ++kc) {
        const int d0 = kc * 32;
        if (kc) __syncthreads();
        #pragma unroll
        for (int j = 0; j < 4; ++j) {
            int g = g0 + arow + j * 16;
            if (g > G4 - 1) g = G4 - 1;
            gl_lds16(wbf + (size_t)g * D_SZ + d0 + akoff,
                     (void*)(Al + (w * 64 + j * 16) * 32));
        }
        gl_lds16(xbf + ((size_t)brow * T_SZ + t) * D_SZ + d0 + akoff,
                 (void*)(Bl + (w * 16) * 32));
        __syncthreads();

        short8 af[4], bv[4];
        #pragma unroll
        for (int s = 0; s < 4; ++s)
            af[s] = *(const short8*)&Al[(w * 64 + s * 16 + col) * 32 + q * 8];
        #pragma unroll
        for (int s = 0; s < 4; ++s)
            bv[s] = *(const short8*)&Bl[(s * 16 + col) * 32 + q * 8];
        #pragma unroll
        for (int gs = 0; gs < 4; ++gs)
            #pragma unroll
            for (int bs = 0; bs < 4; ++bs)
                acc[gs][bs] = __builtin_amdgcn_mfma_f32_16x16x32_bf16(af[gs], bv[bs], acc[gs][bs], 0, 0, 0);
    }

    #pragma unroll
    for (int gs = 0; gs < 4; ++gs) {
        const int S = blockIdx.z * 16 + w * 4 + gs;
        if (S < NSUB) {
            const int gq = S * 16 + q * 4;
            const float4 bi = *(const float4*)&bih[gq];
            const float4 bh = *(const float4*)&bhh[gq];
            #pragma unroll
            for (int bs = 0; bs < 4; ++bs) {
                f32x4 a = acc[gs][bs];
                unsigned lo = (unsigned)f2bf(a[0] + bi.x + bh.x) |
                              ((unsigned)f2bf(a[1] + bi.y + bh.y) << 16);
                unsigned hi = (unsigned)f2bf(a[2] + bi.z + bh.z) |
                              ((unsigned)f2bf(a[3] + bi.w + bh.w) << 16);
                const size_t idx = (((size_t)tt * NSUB + S) * 4 + q) * 512 + (b0 + bs * 16 + col);
                ((uint2*)pre)[idx] = make_uint2(lo, hi);
            }
        }
    }
}

// ---------------------------------------------------------------------------
// Kernel 2: LSTM recurrence. 256 WGs x 512 thr (8 waves); 2 batches per WG.
// Waves 0,1 own 7 gate-subtiles; waves 2..7 own 6 (no dummy MFMAs).
// pre + Wout staged per 8 steps into double-buffered LDS via global_load_lds.
// Gate stores exec-masked to the 8 valid lanes (col<2) — no dump zone.
// ---------------------------------------------------------------------------
__global__ __launch_bounds__(512, 2)
void lstm_rec(const unsigned short* __restrict__ pre,  // [ct][50][4][512][4] bf16
              const float* __restrict__ Whh,
              const unsigned short* __restrict__ woutbf, // [512][200] bf16
              const float* __restrict__ bout,
              float* __restrict__ state,       // h,c,oa each [512][200]
              float* __restrict__ out,
              int t0, int C_T)
{
    const int bk = blockIdx.x;
    const int cidx = (bk >> 3) + (bk & 7) * 32;   // XCD swizzle: line-sharers co-XCD
    const int b0 = cidx * 2;

    const int tid = threadIdx.x, lane = tid & 63, wv = tid >> 6;
    const int col = lane & 15, q = lane >> 4;

    __shared__ __align__(16) unsigned short preS[2 * BS * 1600];  // 51.2 KB
    __shared__ __align__(16) unsigned short woutS[2 * BS * 200];  //  6.4 KB
    __shared__ __align__(16) float gates[2 * GST8];               //  6.5 KB
    __shared__ __align__(16) short hT[3 * HTS];                   //  1.4 KB
    __shared__ float redbuf[8];

    // waves 0,1 -> 7 tiles; waves 2..7 -> 6 tiles
    const bool w7 = (wv < 2);
    const int tbase = w7 ? wv * 7 : 14 + (wv - 2) * 6;

    int gaddr[7], pofs[7];
    #pragma unroll
    for (int j = 0; j < 7; ++j) {
        const int tr = tbase + j;
        const int tj = tr > 49 ? 49 : tr;
        gaddr[j] = col * GST8 + tj * 16 + q * 4;
        pofs[j]  = (tj * 4 + q) * 8 + (col & 1) * 4;   // shorts, within step slab
    }

    // ---- W_hh fragments (bf16): 6 x K=32 chunks + one K=16 tail ----
    short8 aw[7][6];
#if __has_builtin(__builtin_amdgcn_mfma_f32_16x16x16bf16_1k)
    short4v aw6[7];
#else
    short8 aw6[7];
#endif
    #pragma unroll
    for (int j = 0; j < 7; ++j) {
        const int tr = tbase + j;
        const int g = (tr > 49 ? 49 : tr) * 16 + col;
        const float* wr = Whh + (size_t)g * H_SZ;
        #pragma unroll
        for (int kc = 0; kc < 6; ++kc) {
            const int k = kc * 32 + q * 8;
            float4 f0 = *(const float4*)(wr + k);
            float4 f1 = *(const float4*)(wr + k + 4);
            short8 s;
            s[0] = (short)f2bf(f0.x); s[1] = (short)f2bf(f0.y);
            s[2] = (short)f2bf(f0.z); s[3] = (short)f2bf(f0.w);
            s[4] = (short)f2bf(f1.x); s[5] = (short)f2bf(f1.y);
            s[6] = (short)f2bf(f1.z); s[7] = (short)f2bf(f1.w);
            aw[j][kc] = s;
        }
#if __has_builtin(__builtin_amdgcn_mfma_f32_16x16x16bf16_1k)
        short4v t4 = (short4v)0;
        if (q < 2) {
            float4 f = *(const float4*)(wr + 192 + q * 4);
            t4[0] = (short)f2bf(f.x); t4[1] = (short)f2bf(f.y);
            t4[2] = (short)f2bf(f.z); t4[3] = (short)f2bf(f.w);
        }
        aw6[j] = t4;
#else
        short8 t8 = (short8)0;
        if (q == 0) {
            float4 f0 = *(const float4*)(wr + 192);
            float4 f1 = *(const float4*)(wr + 196);
            t8[0] = (short)f2bf(f0.x); t8[1] = (short)f2bf(f0.y);
            t8[2] = (short)f2bf(f0.z); t8[3] = (short)f2bf(f0.w);
            t8[4] = (short)f2bf(f1.x); t8[5] = (short)f2bf(f1.y);
            t8[6] = (short)f2bf(f1.z); t8[7] = (short)f2bf(f1.w);
        }
        aw6[j] = t8;
#endif
    }

    float* h_st  = state;
    float* c_st  = state + (size_t)B_SZ * H_SZ;
    float* oa_st = state + (size_t)2 * B_SZ * H_SZ;

    // ---- init hT (rows 0,1 = h for 2 batches; row 2 = zeros; k>=200 zeros)
    for (int i = tid; i < 3 * HTS; i += 512) {
        const int r = i / HTS, k = i - r * HTS;
        short v = 0;
        if (t0 > 0 && r < 2 && k < H_SZ) v = (short)f2bf(h_st[(size_t)(b0 + r) * H_SZ + k]);
        hT[i] = v;
    }

    // ---- elementwise thread state ----
    const int n_ew = tid >> 8;
    const int h_ew = tid & 255;
    const bool ewv = (h_ew < H_SZ);
    float c_v = 0.f, oa_v = 0.f, hv_last = 0.f;
    if (ewv && t0 > 0) {
        c_v  = c_st [(size_t)(b0 + n_ew) * H_SZ + h_ew];
        oa_v = oa_st[(size_t)(b0 + n_ew) * H_SZ + h_ew];
    }

    const int nblk = C_T / BS;
    const char* preb = (const char*)pre;

    // ---- stage block 0 into buffer 0 (wave wv stages step wv) ----
    {
        const char* src = preb + ((size_t)wv * 200) * 4096 + (size_t)b0 * 8;
        unsigned short* dst = preS + wv * 1600;
        gl_lds16(src + (size_t)lane * 4096,         dst);
        gl_lds16(src + (size_t)(lane + 64) * 4096,  dst + 512);
        gl_lds16(src + (size_t)(lane + 128) * 4096, dst + 1024);
        gl_lds16(src + (size_t)(lane + 136) * 4096, dst + 1088);
        if (lane < 25)
            gl_lds16(woutbf + ((size_t)(t0 + wv) * H_SZ + lane * 8), woutS + wv * 200);
    }
    __syncthreads();

    const short* hrow = hT + (col < 2 ? col : 2) * HTS;

    for (int blk = 0; blk < nblk; ++blk) {
        const int bn = blk & 1;
        // stage next block (clamped) into other buffer
        {
            const int nb = (blk + 1 < nblk) ? blk + 1 : blk;
            const char* src = preb + ((size_t)(nb * BS + wv) * 200) * 4096 + (size_t)b0 * 8;
            unsigned short* dst = preS + ((bn ^ 1) * BS + wv) * 1600;
            gl_lds16(src + (size_t)lane * 4096,         dst);
            gl_lds16(src + (size_t)(lane + 64) * 4096,  dst + 512);
            gl_lds16(src + (size_t)(lane + 128) * 4096, dst + 1024);
            gl_lds16(src + (size_t)(lane + 136) * 4096, dst + 1088);
            if (lane < 25)
                gl_lds16(woutbf + ((size_t)(t0 + nb * BS + wv) * H_SZ + lane * 8),
                         woutS + ((bn ^ 1) * BS + wv) * 200);
        }
        const unsigned short* psb = preS + bn * (BS * 1600);
        const unsigned short* wsb = woutS + bn * (BS * 200);

        for (int s = 0; s < BS; ++s) {
            const unsigned short* ps = psb + s * 1600;

            // acc init from staged pre (bf16 -> f32)
            f32x4 acc[7];
            #pragma unroll
            for (int j = 0; j < 6; ++j) {
                const uint2 p = *(const uint2*)(ps + pofs[j]);
                f32x4 a;
                a[0] = __builtin_bit_cast(float, p.x << 16);
                a[1] = __builtin_bit_cast(float, p.x & 0xFFFF0000u);
                a[2] = __builtin_bit_cast(float, p.y << 16);
                a[3] = __builtin_bit_cast(float, p.y & 0xFFFF0000u);
                acc[j] = a;
            }
            acc[6] = (f32x4)0.f;
            if (w7) {
                const uint2 p = *(const uint2*)(ps + pofs[6]);
                f32x4 a;
                a[0] = __builtin_bit_cast(float, p.x << 16);
                a[1] = __builtin_bit_cast(float, p.x & 0xFFFF0000u);
                a[2] = __builtin_bit_cast(float, p.y << 16);
                a[3] = __builtin_bit_cast(float, p.y & 0xFFFF0000u);
                acc[6] = a;
            }

            // h fragments (shared across tiles)
            short8 hf[6];
            #pragma unroll
            for (int kc = 0; kc < 6; ++kc)
                hf[kc] = *(const short8*)(hrow + kc * 32 + q * 8);
#if __has_builtin(__builtin_amdgcn_mfma_f32_16x16x16bf16_1k)
            const short4v ht_ = *(const short4v*)(hrow + 192 + q * 4);
#else
            const short8 ht_ = *(const short8*)(hrow + 192 + q * 8);
#endif

            // MFMA: tiles 0..5 uniformly; tile 6 only on waves 0,1
            #pragma unroll
            for (int kc = 0; kc < 6; ++kc)
                #pragma unroll
                for (int j = 0; j < 6; ++j)
                    acc[j] = __builtin_amdgcn_mfma_f32_16x16x32_bf16(aw[j][kc], hf[kc], acc[j], 0, 0, 0);
#if __has_builtin(__builtin_amdgcn_mfma_f32_16x16x16bf16_1k)
            #pragma unroll
            for (int j = 0; j < 6; ++j)
                acc[j] = __builtin_amdgcn_mfma_f32_16x16x16bf16_1k(aw6[j], ht_, acc[j], 0, 0, 0);
#else
            #pragma unroll
            for (int j = 0; j < 6; ++j)
                acc[j] = __builtin_amdgcn_mfma_f32_16x16x32_bf16(aw6[j], ht_, acc[j], 0, 0, 0);
#endif
            if (w7) {
                #pragma unroll
                for (int kc = 0; kc < 6; ++kc)
                    acc[6] = __builtin_amdgcn_mfma_f32_16x16x32_bf16(aw[6][kc], hf[kc], acc[6], 0, 0, 0);
#if __has_builtin(__builtin_amdgcn_mfma_f32_16x16x16bf16_1k)
                acc[6] = __builtin_amdgcn_mfma_f32_16x16x16bf16_1k(aw6[6], ht_, acc[6], 0, 0, 0);
#else
                acc[6] = __builtin_amdgcn_mfma_f32_16x16x32_bf16(aw6[6], ht_, acc[6], 0, 0, 0);
#endif
            }

            // raw gates -> LDS, only the 8 valid lanes (col<2)
            if (col < 2) {
                #pragma unroll
                for (int j = 0; j < 6; ++j)
                    *(f32x4*)&gates[gaddr[j]] = acc[j];
                if (w7) *(f32x4*)&gates[gaddr[6]] = acc[6];
            }
            __syncthreads();

            // elementwise: activations, c/h update, output accumulate
            if (ewv) {
                const int gb = n_ew * GST8 + h_ew;
                const float gi = sigm(gates[gb]);
                const float gf = sigm(gates[gb + 200]);
                const float gg = 2.f * sigm(2.f * gates[gb + 400]) - 1.f;
                const float go = sigm(gates[gb + 600]);
                const float cn = gf * c_v + gi * gg;
                c_v = cn;
                const float hv = go * (2.f * sigm(2.f * cn) - 1.f);
                oa_v += hv * bf2f(wsb[s * 200 + h_ew]);
                hT[n_ew * HTS + h_ew] = (short)f2bf(hv);
                hv_last = hv;
            }
            __syncthreads();
        }
    }

    if (t0 + C_T >= T_SZ) {
        float v = oa_v;   // zero on inactive threads
        #pragma unroll
        for (int off = 32; off; off >>= 1) v += __shfl_down(v, off);
        if (lane == 0) redbuf[wv] = v;
        __syncthreads();
        if (tid < 2)
            out[b0 + tid] = redbuf[tid * 4] + redbuf[tid * 4 + 1] +
                            redbuf[tid * 4 + 2] + redbuf[tid * 4 + 3] + bout[0];
    } else if (ewv) {
        h_st [(size_t)(b0 + n_ew) * H_SZ + h_ew] = hv_last;
        c_st [(size_t)(b0 + n_ew) * H_SZ + h_ew] = c_v;
        oa_st[(size_t)(b0 + n_ew) * H_SZ + h_ew] = oa_v;
    }
}

// ---------------------------------------------------------------------------
extern "C" void kernel_launch(void* const* d_in, const int* in_sizes, int n_in,
                              void* d_out, int out_size, void* d_ws, size_t ws_size,
                              hipStream_t stream)
{
    const float* x    = (const float*)d_in[0];
    const float* Wih  = (const float*)d_in[1];
    const float* Whh  = (const float*)d_in[2];
    const float* bih  = (const float*)d_in[3];
    const float* bhh  = (const float*)d_in[4];
    const float* Wout = (const float*)d_in[5];
    const float* bout = (const float*)d_in[6];
    float* out = (float*)d_out;

    // ws layout: state | xbf | wbf | woutbf | pre
    char* ws = (char*)d_ws;
    float* state = (float*)ws;
    size_t off = (size_t)3 * B_SZ * H_SZ * sizeof(float);
    unsigned short* xbf = (unsigned short*)(ws + off);
    off += (size_t)B_SZ * T_SZ * D_SZ * 2;
    unsigned short* wbf = (unsigned short*)(ws + off);
    off += (size_t)G4 * D_SZ * 2;
    unsigned short* woutbf = (unsigned short*)(ws + off);
    off += (size_t)T_SZ * H_SZ * 2;
    unsigned short* pre = (unsigned short*)(ws + off);

    const size_t per_t = (size_t)NSUB * 4 * 512 * 4 * 2;   // 819,200 B per step
    int ct = 512;
    while (ct > BS && off + (size_t)ct * per_t > ws_size) ct >>= 1;

    cvt_bf16<<<dim3(2048), dim3(256), 0, stream>>>(x, xbf, B_SZ * T_SZ * D_SZ / 4);
    cvt_bf16<<<dim3(64),   dim3(256), 0, stream>>>(Wih, wbf, G4 * D_SZ / 4);
    cvt_bf16<<<dim3(100),  dim3(256), 0, stream>>>(Wout, woutbf, T_SZ * H_SZ / 4);

    for (int t0 = 0; t0 < T_SZ; t0 += ct) {
        pre_gemm<<<dim3(ct, 8, 4), dim3(256), 0, stream>>>(
            xbf, wbf, bih, bhh, pre, t0);
        lstm_rec<<<dim3(256), dim3(512), 0, stream>>>(
            pre, Whh, woutbf, bout, state, out, t0, ct);
    }
}